// Round 6
// baseline (94.313 us; speedup 1.0000x reference)
//
#include <hip/hip_runtime.h>
#include <hip/hip_cooperative_groups.h>
#include <math.h>

namespace cg = cooperative_groups;

#define SEARCH 7
#define PAD 3
#define S2 49
#define KNN 7
#define NCLASSES 20
#define H 64
#define W 2048
#define NPTS 131072
#define NTILES 32
#define TROWS 70                 /* rows -3..66 (zero-padded) */
#define TCOLS 70                 /* cols -3..66 (circular)    */
#define BUCKET_CAP 8192
#define BPT 8                    /* blocks per tile */
#define BLOCK 512
#define GRID (NTILES * BPT)      /* 256 blocks: 1/CU guaranteed co-resident */
#define GSTRIDE 16               /* gcur padding: one counter per 64B line */

struct InvG { float v[S2]; };

// sorted-ascending insert into named u64 registers s0..s6 (keys unique)
#define INS(KEY) do {                                                   \
    unsigned long long _k = (KEY);                                      \
    bool i0 = _k < s0, i1 = _k < s1, i2 = _k < s2, i3 = _k < s3,        \
         i4 = _k < s4, i5 = _k < s5, i6 = _k < s6;                      \
    s6 = i6 ? (i5 ? s5 : _k) : s6;                                      \
    s5 = i5 ? (i4 ? s4 : _k) : s5;                                      \
    s4 = i4 ? (i3 ? s3 : _k) : s4;                                      \
    s3 = i3 ? (i2 ? s2 : _k) : s3;                                      \
    s2 = i2 ? (i1 ? s1 : _k) : s2;                                      \
    s1 = i1 ? (i0 ? s0 : _k) : s1;                                      \
    s0 = i0 ? _k : s0;                                                  \
} while (0)

__global__ __launch_bounds__(BLOCK, 2) void fused_kernel(
    const float* __restrict__ proj_range,
    const float* __restrict__ unproj_range,
    const int* __restrict__ proj_argmax,
    const int* __restrict__ pxv,
    const int* __restrict__ pyv,
    int* __restrict__ gcur,
    unsigned* __restrict__ idxbuf,
    int* __restrict__ outv,
    InvG invg)
{
    __shared__ float         ftile[TROWS * TCOLS];
    __shared__ unsigned char atile[TROWS * TCOLS];
    __shared__ int lcnt[NTILES];
    __shared__ int gbase[NTILES];
    __shared__ int scount;

    cg::grid_group gg = cg::this_grid();
    const int tid = threadIdx.x;
    const int bid = blockIdx.x;

    // ---- phase 0: zero padded global bucket counters (exactly once, block 0)
    if (bid == 0) atomicExch(&gcur[tid], 0);          // tid 0..511 covers 32*16
    if (tid < NTILES) lcnt[tid] = 0;
    gg.sync();

    // ---- phase A: scatter this block's 512 points (proven R3/R4 logic)
    {
        int si = bid * BLOCK + tid;                   // 256*512 = NPTS exactly
        int sx = pxv[si];
        int sy = pyv[si];
        int st = sx >> 6;
        int slpos = atomicAdd(&lcnt[st], 1);
        __syncthreads();
        if (tid < NTILES) gbase[tid] = atomicAdd(&gcur[tid * GSTRIDE], lcnt[tid]);
        __syncthreads();
        unsigned packed = (unsigned)si | ((unsigned)(sx & 63) << 17) | ((unsigned)sy << 23);
        idxbuf[st * BUCKET_CAP + gbase[st] + slpos] = packed;
    }
    gg.sync();

    // ---- phase B: per-tile LDS-staged KNN (per-thread full 49, proven R4)
    const int t = bid >> 3;                           // 8 blocks per tile
    const int sub = bid & 7;
    const int tbase = t << 6;
    {
        int lane = tid & 63;
        int q = tid >> 6;                             // 0..7
#pragma unroll
        for (int it = 0; it < 9; ++it) {
            int r = it * 8 + q;
            if (r < TROWS) {
                int sr = r - 3;
                bool vr = (unsigned)sr < (unsigned)H;
                int gb = (vr ? sr : 0) * W;
                int ca = (tbase - 3 + lane) & (W - 1);
                float fv = proj_range[gb + ca];
                int   av = proj_argmax[gb + ca];
                ftile[r * TCOLS + lane] = vr ? fv : 0.0f;
                atile[r * TCOLS + lane] = (unsigned char)(vr ? av : 0);
                if (lane < TCOLS - 64) {
                    int cb = (tbase - 3 + 64 + lane) & (W - 1);
                    float fv2 = proj_range[gb + cb];
                    int   av2 = proj_argmax[gb + cb];
                    ftile[r * TCOLS + 64 + lane] = vr ? fv2 : 0.0f;
                    atile[r * TCOLS + 64 + lane] = (unsigned char)(vr ? av2 : 0);
                }
            }
        }
    }
    if (tid == 0) scount = atomicAdd(&gcur[t * GSTRIDE], 0);   // device-scope load
    __syncthreads();
    const int count = scount;

    for (int slot = sub * BLOCK + tid; slot < count; slot += BPT * BLOCK) {
        unsigned pk = idxbuf[t * BUCKET_CAP + slot];
        int i  = (int)(pk & 0x1FFFFu);
        int xl = (int)((pk >> 17) & 63u);
        int y  = (int)((pk >> 23) & 63u);
        float u = unproj_range[i];

        unsigned long long s0 = ~0ull, s1 = ~0ull, s2 = ~0ull, s3 = ~0ull,
                           s4 = ~0ull, s5 = ~0ull, s6 = ~0ull;

        INS(24ull);   // center candidate: dist exactly 0, j=24

#pragma unroll
        for (int dy = -PAD; dy <= PAD; ++dy) {
            int base = (y + dy + 3) * TCOLS + xl + 3;
#pragma unroll
            for (int dx = -PAD; dx <= PAD; ++dx) {
                const int j = (dy + PAD) * SEARCH + (dx + PAD);
                if (j == (S2 - 1) / 2) continue;       // center handled above
                float nb = ftile[base + dx];
                nb = (nb < 0.0f) ? __builtin_inff() : nb;
                float d = fabsf(nb - u) * invg.v[j];
                INS(((unsigned long long)__float_as_uint(d) << 6) | (unsigned)j);
            }
        }

        int c0, c1, c2, c3, c4, c5, c6;
#define CLSK(K, CK) do {                                                 \
        unsigned long long key = s##K;                                   \
        int j = (int)(key & 63u);                                        \
        bool sel = (key >> 6) <= 0x3f800000ull;                          \
        int dy7 = (j * 37) >> 8;                                         \
        int cc = (int)atile[(y + dy7) * TCOLS + xl + (j - dy7 * 7)];     \
        CK = sel ? cc : 0;                                               \
    } while (0)
        CLSK(0, c0); CLSK(1, c1); CLSK(2, c2); CLSK(3, c3);
        CLSK(4, c4); CLSK(5, c5); CLSK(6, c6);
#undef CLSK

        int n0 = 1, n1 = 1, n2 = 1, n3 = 1, n4 = 1, n5 = 1, n6 = 1;
#define PAIRV(A, B) do { bool e = (c##A == c##B); n##A += e ? 1 : 0; n##B += e ? 1 : 0; } while (0)
        PAIRV(0,1); PAIRV(0,2); PAIRV(0,3); PAIRV(0,4); PAIRV(0,5); PAIRV(0,6);
        PAIRV(1,2); PAIRV(1,3); PAIRV(1,4); PAIRV(1,5); PAIRV(1,6);
        PAIRV(2,3); PAIRV(2,4); PAIRV(2,5); PAIRV(2,6);
        PAIRV(3,4); PAIRV(3,5); PAIRV(3,6);
        PAIRV(4,5); PAIRV(4,6);
        PAIRV(5,6);
#undef PAIRV

        int best = 0;
#define SCORE(K) do {                                                    \
        bool valid = (unsigned)(c##K - 1) < (unsigned)(NCLASSES - 1);    \
        int sc = valid ? ((n##K << 5) | (31 - c##K)) : 0;                \
        best = max(best, sc);                                            \
    } while (0)
        SCORE(0); SCORE(1); SCORE(2); SCORE(3); SCORE(4); SCORE(5); SCORE(6);
#undef SCORE
        outv[i] = (best == 0) ? 1 : (31 - (best & 31));
    }
}

extern "C" void kernel_launch(void* const* d_in, const int* in_sizes, int n_in,
                              void* d_out, int out_size, void* d_ws, size_t ws_size,
                              hipStream_t stream) {
    const float* proj_range   = (const float*)d_in[0];
    const float* unproj_range = (const float*)d_in[1];
    const int*   proj_argmax  = (const int*)d_in[2];
    const int*   px           = (const int*)d_in[3];
    const int*   py           = (const int*)d_in[4];
    int* out = (int*)d_out;

    int*      gcur   = (int*)d_ws;                       // 512 padded ints
    unsigned* idxbuf = (unsigned*)((char*)d_ws + 4096);

    // Emulate numpy float32 pipeline for the inverse-gaussian table.
    InvG invg;
    float g[S2];
    for (int yy = 0; yy < SEARCH; ++yy) {
        for (int xx = 0; xx < SEARCH; ++xx) {
            float fdx = (float)xx - 3.0f;
            float fdy = (float)yy - 3.0f;
            float s   = fdx * fdx + fdy * fdy;
            float arg = -s / 2.0f;
            float e   = (float)exp((double)arg);
            float gg  = e / 6.2831855f;
            g[yy * SEARCH + xx] = gg;
        }
    }
    float r[8];
    for (int tt = 0; tt < 8; ++tt) r[tt] = g[tt];
    int ii;
    for (ii = 8; ii + 8 <= 48; ii += 8)
        for (int tt = 0; tt < 8; ++tt) r[tt] += g[ii + tt];
    float ssum = ((r[0] + r[1]) + (r[2] + r[3])) + ((r[4] + r[5]) + (r[6] + r[7]));
    for (; ii < S2; ++ii) ssum += g[ii];
    for (int tt = 0; tt < S2; ++tt) invg.v[tt] = 1.0f - (g[tt] / ssum);

    void* args[] = { (void*)&proj_range, (void*)&unproj_range, (void*)&proj_argmax,
                     (void*)&px, (void*)&py, (void*)&gcur, (void*)&idxbuf,
                     (void*)&out, (void*)&invg };
    hipLaunchCooperativeKernel((const void*)fused_kernel, dim3(GRID), dim3(BLOCK),
                               args, 0, stream);
}

// Round 7
// 33.747 us; speedup vs baseline: 2.7947x; 2.7947x over previous
//
#include <hip/hip_runtime.h>
#include <math.h>

#define SEARCH 7
#define PAD 3
#define S2 49
#define KNN 7
#define NCLASSES 20
#define H 64
#define W 2048
#define NPTS 131072
#define NTILES 32
#define TROWS 70                 /* rows -3..66 (zero-padded) */
#define TCOLS 70                 /* cols -3..66 (circular)    */
#define BUCKET_CAP 8192
#define BPT 32                   /* knn blocks per tile */
#define KBLOCK 256
#define PPB 128                  /* points per block-iteration (2 wave-pairs) */

struct InvG { float v[S2]; };

// Bucket points by px tile. Packed entry: i | (px&63)<<17 | py<<23.  (R4-proven)
__global__ __launch_bounds__(1024) void scatter_kernel(
    const int* __restrict__ pxv, const int* __restrict__ pyv,
    int* __restrict__ gcur, unsigned* __restrict__ idxbuf)
{
    __shared__ int lcnt[NTILES];
    __shared__ int gbase[NTILES];
    int tid = threadIdx.x;
    if (tid < NTILES) lcnt[tid] = 0;
    __syncthreads();
    int i = blockIdx.x * 1024 + tid;
    int x = pxv[i];
    int y = pyv[i];
    int t = x >> 6;
    int lpos = atomicAdd(&lcnt[t], 1);
    __syncthreads();
    if (tid < NTILES) gbase[tid] = atomicAdd(&gcur[tid], lcnt[tid]);
    __syncthreads();
    unsigned packed = (unsigned)i | ((unsigned)(x & 63) << 17) | ((unsigned)y << 23);
    idxbuf[t * BUCKET_CAP + gbase[t] + lpos] = packed;
}

// sorted-ascending insert into named u64 registers s0..s6 (keys unique)
#define INS(KEY) do {                                                   \
    unsigned long long _k = (KEY);                                      \
    bool i0 = _k < s0, i1 = _k < s1, i2 = _k < s2, i3 = _k < s3,        \
         i4 = _k < s4, i5 = _k < s5, i6 = _k < s6;                      \
    s6 = i6 ? (i5 ? s5 : _k) : s6;                                      \
    s5 = i5 ? (i4 ? s4 : _k) : s5;                                      \
    s4 = i4 ? (i3 ? s3 : _k) : s4;                                      \
    s3 = i3 ? (i2 ? s2 : _k) : s3;                                      \
    s2 = i2 ? (i1 ? s1 : _k) : s2;                                      \
    s1 = i1 ? (i0 ? s0 : _k) : s1;                                      \
    s0 = i0 ? _k : s0;                                                  \
} while (0)

#define CAND(J, RB, DX) do {                                            \
    float nb = ftile[(RB) + (DX)];                                      \
    nb = (nb < 0.0f) ? __builtin_inff() : nb;                           \
    float d = fabsf(nb - u) * invg.v[J];                                \
    INS(((unsigned long long)__float_as_uint(d) << 6) | (unsigned)(J)); \
} while (0)

__global__ __launch_bounds__(KBLOCK, 4) void knn_kernel(
    const float* __restrict__ proj_range,
    const float* __restrict__ unproj_range,
    const int* __restrict__ proj_argmax,
    const int* __restrict__ gcur,
    const unsigned* __restrict__ idxbuf,
    int* __restrict__ outv,
    InvG invg)
{
    __shared__ float         ftile[TROWS * TCOLS];
    __shared__ unsigned char atile[TROWS * TCOLS];
    __shared__ unsigned long long kbuf[PPB][KNN];

    const int tid = threadIdx.x;
    const int t = blockIdx.x >> 5;           // 32 blocks per tile
    const int sub = blockIdx.x & 31;
    const int tbase = t << 6;
    const int lane = tid & 63;
    const int wave = tid >> 6;               // 0..3

    // stage 70x70 padded tiles (R4/R6-proven; u8 classes)
#pragma unroll
    for (int it = 0; it < 18; ++it) {
        int r = it * 4 + wave;
        if (r < TROWS) {
            int sr = r - 3;
            bool vr = (unsigned)sr < (unsigned)H;
            int gb = (vr ? sr : 0) * W;
            int ca = (tbase - 3 + lane) & (W - 1);
            float fv = proj_range[gb + ca];
            int   av = proj_argmax[gb + ca];
            ftile[r * TCOLS + lane] = vr ? fv : 0.0f;
            atile[r * TCOLS + lane] = (unsigned char)(vr ? av : 0);
            if (lane < TCOLS - 64) {
                int cb = (tbase - 3 + 64 + lane) & (W - 1);
                float fv2 = proj_range[gb + cb];
                int   av2 = proj_argmax[gb + cb];
                ftile[r * TCOLS + 64 + lane] = vr ? fv2 : 0.0f;
                atile[r * TCOLS + 64 + lane] = (unsigned char)(vr ? av2 : 0);
            }
        }
    }
    __syncthreads();

    const int count = gcur[t];
    const int pairp = wave >> 1;             // 0..1
    const int role  = wave & 1;              // wave-uniform
    const int pidx  = pairp * 64 + lane;     // 0..127

    for (int base = sub * PPB; base < count; base += BPT * PPB) {
        int slot = base + pidx;
        bool active = slot < count;
        unsigned pk = active ? idxbuf[t * BUCKET_CAP + slot] : 0u;
        int i  = (int)(pk & 0x1FFFFu);
        int xl = (int)((pk >> 17) & 63u);
        int y  = (int)((pk >> 23) & 63u);
        float u = unproj_range[i];

        unsigned long long s0 = ~0ull, s1 = ~0ull, s2 = ~0ull, s3 = ~0ull,
                           s4 = ~0ull, s5 = ~0ull, s6 = ~0ull;

        if (role == 0) {
            // j = 0..23 : rows dy=-3..-1 full, dy=0 dx=-3..-1   (R1-proven split)
#pragma unroll
            for (int dy = -3; dy <= 0; ++dy) {
                int rb = (y + dy + 3) * TCOLS + xl + 3;
                const int dxmax = (dy == 0) ? -1 : 3;
#pragma unroll
                for (int dx = -3; dx <= dxmax; ++dx) {
                    const int j = (dy + 3) * 7 + (dx + 3);
                    CAND(j, rb, dx);
                }
            }
        } else {
            INS(24ull);                      // center: dist exactly 0, j=24
            // j = 25..48 : dy=0 dx=1..3, rows dy=1..3 full
#pragma unroll
            for (int dy = 0; dy <= 3; ++dy) {
                int rb = (y + dy + 3) * TCOLS + xl + 3;
                const int dxmin = (dy == 0) ? 1 : -3;
#pragma unroll
                for (int dx = dxmin; dx <= 3; ++dx) {
                    const int j = (dy + 3) * 7 + (dx + 3);
                    CAND(j, rb, dx);
                }
            }
            kbuf[pidx][0] = s0; kbuf[pidx][1] = s1; kbuf[pidx][2] = s2;
            kbuf[pidx][3] = s3; kbuf[pidx][4] = s4; kbuf[pidx][5] = s5;
            kbuf[pidx][6] = s6;
        }
        __syncthreads();

        if (role == 0) {
            // Batcher half-cleaner: mins of (a_k, b_{6-k}) = 7 smallest of 14 (R1-proven)
            unsigned long long b;
            b = kbuf[pidx][6]; unsigned long long m0 = s0 < b ? s0 : b;
            b = kbuf[pidx][5]; unsigned long long m1 = s1 < b ? s1 : b;
            b = kbuf[pidx][4]; unsigned long long m2 = s2 < b ? s2 : b;
            b = kbuf[pidx][3]; unsigned long long m3 = s3 < b ? s3 : b;
            b = kbuf[pidx][2]; unsigned long long m4 = s4 < b ? s4 : b;
            b = kbuf[pidx][1]; unsigned long long m5 = s5 < b ? s5 : b;
            b = kbuf[pidx][0]; unsigned long long m6 = s6 < b ? s6 : b;

            int c0, c1, c2, c3, c4, c5, c6;
#define CLSK(MK, CK) do {                                                \
            unsigned long long key = MK;                                 \
            int j = (int)(key & 63u);                                    \
            bool sel = (key >> 6) <= 0x3f800000ull;                      \
            int dy7 = (j * 37) >> 8;                                     \
            int cc = (int)atile[(y + dy7) * TCOLS + xl + (j - dy7 * 7)]; \
            CK = sel ? cc : 0;                                           \
        } while (0)
            CLSK(m0, c0); CLSK(m1, c1); CLSK(m2, c2); CLSK(m3, c3);
            CLSK(m4, c4); CLSK(m5, c5); CLSK(m6, c6);
#undef CLSK

            int n0 = 1, n1 = 1, n2 = 1, n3 = 1, n4 = 1, n5 = 1, n6 = 1;
#define PAIRV(A, B) do { bool e = (c##A == c##B); n##A += e ? 1 : 0; n##B += e ? 1 : 0; } while (0)
            PAIRV(0,1); PAIRV(0,2); PAIRV(0,3); PAIRV(0,4); PAIRV(0,5); PAIRV(0,6);
            PAIRV(1,2); PAIRV(1,3); PAIRV(1,4); PAIRV(1,5); PAIRV(1,6);
            PAIRV(2,3); PAIRV(2,4); PAIRV(2,5); PAIRV(2,6);
            PAIRV(3,4); PAIRV(3,5); PAIRV(3,6);
            PAIRV(4,5); PAIRV(4,6);
            PAIRV(5,6);
#undef PAIRV

            int best = 0;
#define SCORE(K) do {                                                    \
            bool valid = (unsigned)(c##K - 1) < (unsigned)(NCLASSES - 1);\
            int sc = valid ? ((n##K << 5) | (31 - c##K)) : 0;            \
            best = max(best, sc);                                        \
        } while (0)
            SCORE(0); SCORE(1); SCORE(2); SCORE(3); SCORE(4); SCORE(5); SCORE(6);
#undef SCORE
            if (active) outv[i] = (best == 0) ? 1 : (31 - (best & 31));
        }
        __syncthreads();                     // protect kbuf before next iteration
    }
}

extern "C" void kernel_launch(void* const* d_in, const int* in_sizes, int n_in,
                              void* d_out, int out_size, void* d_ws, size_t ws_size,
                              hipStream_t stream) {
    const float* proj_range   = (const float*)d_in[0];
    const float* unproj_range = (const float*)d_in[1];
    const int*   proj_argmax  = (const int*)d_in[2];
    const int*   px           = (const int*)d_in[3];
    const int*   py           = (const int*)d_in[4];
    int* out = (int*)d_out;

    int*      gcur   = (int*)d_ws;
    unsigned* idxbuf = (unsigned*)((char*)d_ws + 1024);

    // Emulate numpy float32 pipeline for the inverse-gaussian table.
    InvG invg;
    float g[S2];
    for (int yy = 0; yy < SEARCH; ++yy) {
        for (int xx = 0; xx < SEARCH; ++xx) {
            float fdx = (float)xx - 3.0f;
            float fdy = (float)yy - 3.0f;
            float s   = fdx * fdx + fdy * fdy;
            float arg = -s / 2.0f;
            float e   = (float)exp((double)arg);
            float gg  = e / 6.2831855f;
            g[yy * SEARCH + xx] = gg;
        }
    }
    float r[8];
    for (int tt = 0; tt < 8; ++tt) r[tt] = g[tt];
    int ii;
    for (ii = 8; ii + 8 <= 48; ii += 8)
        for (int tt = 0; tt < 8; ++tt) r[tt] += g[ii + tt];
    float ssum = ((r[0] + r[1]) + (r[2] + r[3])) + ((r[4] + r[5]) + (r[6] + r[7]));
    for (; ii < S2; ++ii) ssum += g[ii];
    for (int tt = 0; tt < S2; ++tt) invg.v[tt] = 1.0f - (g[tt] / ssum);

    hipMemsetAsync(d_ws, 0, NTILES * sizeof(int), stream);
    scatter_kernel<<<NPTS / 1024, 1024, 0, stream>>>(px, py, gcur, idxbuf);
    knn_kernel<<<NTILES * BPT, KBLOCK, 0, stream>>>(
        proj_range, unproj_range, proj_argmax, gcur, idxbuf, out, invg);
}

// Round 8
// 27.489 us; speedup vs baseline: 3.4309x; 1.2276x over previous
//
#include <hip/hip_runtime.h>
#include <math.h>

#define SEARCH 7
#define PAD 3
#define S2 49
#define KNN 7
#define NCLASSES 20
#define H 64
#define W 2048
#define NPTS 131072
#define NTILES 32
#define TROWS 70                 /* rows -3..66 (zero-padded) */
#define TCOLS 70                 /* cols -3..66 (circular)    */
#define SPT 32                   /* sub-blocks per tile */
#define SLICE (NPTS / SPT)       /* 4096 points scanned per block */
#define KBLOCK 256
#define PPB 128                  /* points per pair-iteration */
#define QCAP 512

struct InvG { float v[S2]; };

// sorted-ascending insert into named u64 registers s0..s6 (keys unique)
#define INS(KEY) do {                                                   \
    unsigned long long _k = (KEY);                                      \
    bool i0 = _k < s0, i1 = _k < s1, i2 = _k < s2, i3 = _k < s3,        \
         i4 = _k < s4, i5 = _k < s5, i6 = _k < s6;                      \
    s6 = i6 ? (i5 ? s5 : _k) : s6;                                      \
    s5 = i5 ? (i4 ? s4 : _k) : s5;                                      \
    s4 = i4 ? (i3 ? s3 : _k) : s4;                                      \
    s3 = i3 ? (i2 ? s2 : _k) : s3;                                      \
    s2 = i2 ? (i1 ? s1 : _k) : s2;                                      \
    s1 = i1 ? (i0 ? s0 : _k) : s1;                                      \
    s0 = i0 ? _k : s0;                                                  \
} while (0)

#define CAND(J, RB, DX) do {                                            \
    float nb = ftile[(RB) + (DX)];                                      \
    nb = (nb < 0.0f) ? __builtin_inff() : nb;                           \
    float d = fabsf(nb - u) * invg.v[J];                                \
    INS(((unsigned long long)__float_as_uint(d) << 6) | (unsigned)(J)); \
} while (0)

__global__ __launch_bounds__(KBLOCK, 4) void knn_kernel(
    const float* __restrict__ proj_range,
    const float* __restrict__ unproj_range,
    const int* __restrict__ proj_argmax,
    const int* __restrict__ pxv,
    const int* __restrict__ pyv,
    int* __restrict__ outv,
    InvG invg)
{
    __shared__ float         ftile[TROWS * TCOLS];
    __shared__ unsigned char atile[TROWS * TCOLS];
    __shared__ unsigned long long kbuf[PPB][KNN];
    __shared__ unsigned queue[QCAP];
    __shared__ int qcnt;

    const int tid  = threadIdx.x;
    const int t    = blockIdx.x >> 5;        // tile
    const int sub  = blockIdx.x & 31;        // slice
    const int tbase = t << 6;
    const int lane = tid & 63;
    const int wave = tid >> 6;               // 0..3

    if (tid == 0) qcnt = 0;

    // stage 70x70 padded tiles (R4/R7-proven; u8 classes)
#pragma unroll
    for (int it = 0; it < 18; ++it) {
        int r = it * 4 + wave;
        if (r < TROWS) {
            int sr = r - 3;
            bool vr = (unsigned)sr < (unsigned)H;
            int gb = (vr ? sr : 0) * W;
            int ca = (tbase - 3 + lane) & (W - 1);
            float fv = proj_range[gb + ca];
            int   av = proj_argmax[gb + ca];
            ftile[r * TCOLS + lane] = vr ? fv : 0.0f;
            atile[r * TCOLS + lane] = (unsigned char)(vr ? av : 0);
            if (lane < TCOLS - 64) {
                int cb = (tbase - 3 + 64 + lane) & (W - 1);
                float fv2 = proj_range[gb + cb];
                int   av2 = proj_argmax[gb + cb];
                ftile[r * TCOLS + 64 + lane] = vr ? fv2 : 0.0f;
                atile[r * TCOLS + 64 + lane] = (unsigned char)(vr ? av2 : 0);
            }
        }
    }
    __syncthreads();                          // tiles ready, qcnt=0 visible

    // scan own slice of px; enqueue matches (px>>6 == t)
    {
        const int4* px4 = (const int4*)pxv;
        int base4 = (sub * SLICE) >> 2;       // int4-aligned
#pragma unroll
        for (int k = 0; k < 4; ++k) {
            int idx4 = base4 + k * KBLOCK + tid;
            int4 v = px4[idx4];
            int i0x = idx4 * 4;
#pragma unroll
            for (int e = 0; e < 4; ++e) {
                int x = (e == 0) ? v.x : (e == 1) ? v.y : (e == 2) ? v.z : v.w;
                if ((x >> 6) == t) {
                    int i = i0x + e;
                    int y = pyv[i];
                    int pos = atomicAdd(&qcnt, 1);
                    if (pos < QCAP)
                        queue[pos] = (unsigned)i | ((unsigned)(x & 63) << 17)
                                                | ((unsigned)y << 23);
                }
            }
        }
    }
    __syncthreads();
    const int count = min(qcnt, QCAP);

    const int pairp = wave >> 1;             // 0..1
    const int role  = wave & 1;              // wave-uniform
    const int pidx  = pairp * 64 + lane;     // 0..127

    for (int base = 0; base < count; base += PPB) {
        int slot = base + pidx;
        bool active = slot < count;
        unsigned pk = active ? queue[slot] : 0u;
        int i  = (int)(pk & 0x1FFFFu);
        int xl = (int)((pk >> 17) & 63u);
        int y  = (int)((pk >> 23) & 63u);
        float u = unproj_range[i];

        unsigned long long s0 = ~0ull, s1 = ~0ull, s2 = ~0ull, s3 = ~0ull,
                           s4 = ~0ull, s5 = ~0ull, s6 = ~0ull;

        if (role == 0) {
            // j = 0..23 : rows dy=-3..-1 full, dy=0 dx=-3..-1   (R1/R7-proven split)
#pragma unroll
            for (int dy = -3; dy <= 0; ++dy) {
                int rb = (y + dy + 3) * TCOLS + xl + 3;
                const int dxmax = (dy == 0) ? -1 : 3;
#pragma unroll
                for (int dx = -3; dx <= dxmax; ++dx) {
                    const int j = (dy + 3) * 7 + (dx + 3);
                    CAND(j, rb, dx);
                }
            }
        } else {
            INS(24ull);                      // center: dist exactly 0, j=24
#pragma unroll
            for (int dy = 0; dy <= 3; ++dy) {
                int rb = (y + dy + 3) * TCOLS + xl + 3;
                const int dxmin = (dy == 0) ? 1 : -3;
#pragma unroll
                for (int dx = dxmin; dx <= 3; ++dx) {
                    const int j = (dy + 3) * 7 + (dx + 3);
                    CAND(j, rb, dx);
                }
            }
            kbuf[pidx][0] = s0; kbuf[pidx][1] = s1; kbuf[pidx][2] = s2;
            kbuf[pidx][3] = s3; kbuf[pidx][4] = s4; kbuf[pidx][5] = s5;
            kbuf[pidx][6] = s6;
        }
        __syncthreads();

        if (role == 0) {
            // Batcher half-cleaner: mins of (a_k, b_{6-k}) = 7 smallest of 14
            unsigned long long b;
            b = kbuf[pidx][6]; unsigned long long m0 = s0 < b ? s0 : b;
            b = kbuf[pidx][5]; unsigned long long m1 = s1 < b ? s1 : b;
            b = kbuf[pidx][4]; unsigned long long m2 = s2 < b ? s2 : b;
            b = kbuf[pidx][3]; unsigned long long m3 = s3 < b ? s3 : b;
            b = kbuf[pidx][2]; unsigned long long m4 = s4 < b ? s4 : b;
            b = kbuf[pidx][1]; unsigned long long m5 = s5 < b ? s5 : b;
            b = kbuf[pidx][0]; unsigned long long m6 = s6 < b ? s6 : b;

            int c0, c1, c2, c3, c4, c5, c6;
#define CLSK(MK, CK) do {                                                \
            unsigned long long key = MK;                                 \
            int j = (int)(key & 63u);                                    \
            bool sel = (key >> 6) <= 0x3f800000ull;                      \
            int dy7 = (j * 37) >> 8;                                     \
            int cc = (int)atile[(y + dy7) * TCOLS + xl + (j - dy7 * 7)]; \
            CK = sel ? cc : 0;                                           \
        } while (0)
            CLSK(m0, c0); CLSK(m1, c1); CLSK(m2, c2); CLSK(m3, c3);
            CLSK(m4, c4); CLSK(m5, c5); CLSK(m6, c6);
#undef CLSK

            int n0 = 1, n1 = 1, n2 = 1, n3 = 1, n4 = 1, n5 = 1, n6 = 1;
#define PAIRV(A, B) do { bool e = (c##A == c##B); n##A += e ? 1 : 0; n##B += e ? 1 : 0; } while (0)
            PAIRV(0,1); PAIRV(0,2); PAIRV(0,3); PAIRV(0,4); PAIRV(0,5); PAIRV(0,6);
            PAIRV(1,2); PAIRV(1,3); PAIRV(1,4); PAIRV(1,5); PAIRV(1,6);
            PAIRV(2,3); PAIRV(2,4); PAIRV(2,5); PAIRV(2,6);
            PAIRV(3,4); PAIRV(3,5); PAIRV(3,6);
            PAIRV(4,5); PAIRV(4,6);
            PAIRV(5,6);
#undef PAIRV

            int best = 0;
#define SCORE(K) do {                                                    \
            bool valid = (unsigned)(c##K - 1) < (unsigned)(NCLASSES - 1);\
            int sc = valid ? ((n##K << 5) | (31 - c##K)) : 0;            \
            best = max(best, sc);                                        \
        } while (0)
            SCORE(0); SCORE(1); SCORE(2); SCORE(3); SCORE(4); SCORE(5); SCORE(6);
#undef SCORE
            if (active) outv[i] = (best == 0) ? 1 : (31 - (best & 31));
        }
        __syncthreads();                     // protect kbuf before next iteration
    }
}

extern "C" void kernel_launch(void* const* d_in, const int* in_sizes, int n_in,
                              void* d_out, int out_size, void* d_ws, size_t ws_size,
                              hipStream_t stream) {
    const float* proj_range   = (const float*)d_in[0];
    const float* unproj_range = (const float*)d_in[1];
    const int*   proj_argmax  = (const int*)d_in[2];
    const int*   px           = (const int*)d_in[3];
    const int*   py           = (const int*)d_in[4];
    int* out = (int*)d_out;

    // Emulate numpy float32 pipeline for the inverse-gaussian table.
    InvG invg;
    float g[S2];
    for (int yy = 0; yy < SEARCH; ++yy) {
        for (int xx = 0; xx < SEARCH; ++xx) {
            float fdx = (float)xx - 3.0f;
            float fdy = (float)yy - 3.0f;
            float s   = fdx * fdx + fdy * fdy;
            float arg = -s / 2.0f;
            float e   = (float)exp((double)arg);
            float gg  = e / 6.2831855f;
            g[yy * SEARCH + xx] = gg;
        }
    }
    float r[8];
    for (int tt = 0; tt < 8; ++tt) r[tt] = g[tt];
    int ii;
    for (ii = 8; ii + 8 <= 48; ii += 8)
        for (int tt = 0; tt < 8; ++tt) r[tt] += g[ii + tt];
    float ssum = ((r[0] + r[1]) + (r[2] + r[3])) + ((r[4] + r[5]) + (r[6] + r[7]));
    for (; ii < S2; ++ii) ssum += g[ii];
    for (int tt = 0; tt < S2; ++tt) invg.v[tt] = 1.0f - (g[tt] / ssum);

    knn_kernel<<<NTILES * SPT, KBLOCK, 0, stream>>>(
        proj_range, unproj_range, proj_argmax, px, py, out, invg);
}

// Round 9
// 21.065 us; speedup vs baseline: 4.4773x; 1.3050x over previous
//
#include <hip/hip_runtime.h>
#include <math.h>

#define SEARCH 7
#define PAD 3
#define S2 49
#define KNN 7
#define NCLASSES 20
#define H 64
#define W 2048
#define NPTS 131072
#define NTILES 32
#define TROWS 70                 /* rows -3..66 (zero-padded) */
#define TCOLS 70                 /* cols -3..66 (circular)    */
#define SPT 32                   /* sub-blocks per tile */
#define SLICE (NPTS / SPT)       /* 4096 points scanned per block */
#define KBLOCK 256
#define PPB 128                  /* points per pair-iteration */
#define QCAP 512

// f64-packed key: bits = (1<<62) | (distbits<<6) | j ; positive normal doubles,
// value order == bit order == exact lex-(dist, j) order (proven u64 scheme).
#define SENTINEL_BITS 0x7FE0000000000000ull
#define CUTOFF_KEYMAX 0x4000000FE000003Full   /* (1<<62)|(0x3f800000<<6)|63 */

struct InvG { float v[S2]; };

// min/max bubble insert into sorted doubles s0..s6 (13 f64 ops, keys unique)
#define INSF(KEY) do {                                                  \
    double _x = (KEY);                                                  \
    double _t;                                                          \
    _t = fmin(s0, _x); _x = fmax(s0, _x); s0 = _t;                      \
    _t = fmin(s1, _x); _x = fmax(s1, _x); s1 = _t;                      \
    _t = fmin(s2, _x); _x = fmax(s2, _x); s2 = _t;                      \
    _t = fmin(s3, _x); _x = fmax(s3, _x); s3 = _t;                      \
    _t = fmin(s4, _x); _x = fmax(s4, _x); s4 = _t;                      \
    _t = fmin(s5, _x); _x = fmax(s5, _x); s5 = _t;                      \
    s6 = fmin(s6, _x);                                                  \
} while (0)

#define CAND(J, RB, DX) do {                                            \
    float nb = ftile[(RB) + (DX)];                                      \
    nb = (nb < 0.0f) ? __builtin_inff() : nb;                           \
    float d = fabsf(nb - u) * invg.v[J];                                \
    unsigned long long kb = (1ull << 62)                                \
        | ((unsigned long long)__float_as_uint(d) << 6)                 \
        | (unsigned)(J);                                                \
    INSF(__longlong_as_double((long long)kb));                          \
} while (0)

__global__ __launch_bounds__(KBLOCK, 4) void knn_kernel(
    const float* __restrict__ proj_range,
    const float* __restrict__ unproj_range,
    const int* __restrict__ proj_argmax,
    const int* __restrict__ pxv,
    const int* __restrict__ pyv,
    int* __restrict__ outv,
    InvG invg)
{
    __shared__ float         ftile[TROWS * TCOLS];
    __shared__ unsigned char atile[TROWS * TCOLS];
    __shared__ double        kbuf[PPB][KNN];
    __shared__ unsigned queue[QCAP];
    __shared__ int qcnt;

    const int tid  = threadIdx.x;
    const int t    = blockIdx.x >> 5;        // tile
    const int sub  = blockIdx.x & 31;        // slice
    const int tbase = t << 6;
    const int lane = tid & 63;
    const int wave = tid >> 6;               // 0..3

    if (tid == 0) qcnt = 0;

    // stage 70x70 padded tiles (R4/R7-proven; u8 classes)
#pragma unroll
    for (int it = 0; it < 18; ++it) {
        int r = it * 4 + wave;
        if (r < TROWS) {
            int sr = r - 3;
            bool vr = (unsigned)sr < (unsigned)H;
            int gb = (vr ? sr : 0) * W;
            int ca = (tbase - 3 + lane) & (W - 1);
            float fv = proj_range[gb + ca];
            int   av = proj_argmax[gb + ca];
            ftile[r * TCOLS + lane] = vr ? fv : 0.0f;
            atile[r * TCOLS + lane] = (unsigned char)(vr ? av : 0);
            if (lane < TCOLS - 64) {
                int cb = (tbase - 3 + 64 + lane) & (W - 1);
                float fv2 = proj_range[gb + cb];
                int   av2 = proj_argmax[gb + cb];
                ftile[r * TCOLS + 64 + lane] = vr ? fv2 : 0.0f;
                atile[r * TCOLS + 64 + lane] = (unsigned char)(vr ? av2 : 0);
            }
        }
    }
    __syncthreads();                          // tiles ready, qcnt=0 visible

    // scan own slice of px; enqueue matches (px>>6 == t)  (R8-proven)
    {
        const int4* px4 = (const int4*)pxv;
        int base4 = (sub * SLICE) >> 2;
#pragma unroll
        for (int k = 0; k < 4; ++k) {
            int idx4 = base4 + k * KBLOCK + tid;
            int4 v = px4[idx4];
            int i0x = idx4 * 4;
#pragma unroll
            for (int e = 0; e < 4; ++e) {
                int x = (e == 0) ? v.x : (e == 1) ? v.y : (e == 2) ? v.z : v.w;
                if ((x >> 6) == t) {
                    int i = i0x + e;
                    int y = pyv[i];
                    int pos = atomicAdd(&qcnt, 1);
                    if (pos < QCAP)
                        queue[pos] = (unsigned)i | ((unsigned)(x & 63) << 17)
                                                | ((unsigned)y << 23);
                }
            }
        }
    }
    __syncthreads();
    const int count = min(qcnt, QCAP);

    const int pairp = wave >> 1;             // 0..1
    const int role  = wave & 1;              // wave-uniform
    const int pidx  = pairp * 64 + lane;     // 0..127

    for (int base = 0; base < count; base += PPB) {
        int slot = base + pidx;
        bool active = slot < count;
        bool anyact = __ballot(active) != 0;  // wave-uniform; same for both roles
        unsigned pk = 0u; int i = 0, xl = 0, y = 0;

        if (anyact) {
            pk = active ? queue[slot] : 0u;
            i  = (int)(pk & 0x1FFFFu);
            xl = (int)((pk >> 17) & 63u);
            y  = (int)((pk >> 23) & 63u);
            float u = unproj_range[i];

            double s0, s1, s2, s3, s4, s5, s6;
            s0 = s1 = s2 = s3 = s4 = s5 = s6 =
                __longlong_as_double((long long)SENTINEL_BITS);

            if (role == 0) {
                // j = 0..23 : rows dy=-3..-1 full, dy=0 dx=-3..-1 (proven split)
#pragma unroll
                for (int dy = -3; dy <= 0; ++dy) {
                    int rb = (y + dy + 3) * TCOLS + xl + 3;
                    const int dxmax = (dy == 0) ? -1 : 3;
#pragma unroll
                    for (int dx = -3; dx <= dxmax; ++dx) {
                        const int j = (dy + 3) * 7 + (dx + 3);
                        CAND(j, rb, dx);
                    }
                }
                // stash own sorted 7 for after the barrier via registers
            } else {
                INSF(__longlong_as_double((long long)((1ull << 62) | 24ull)));
#pragma unroll
                for (int dy = 0; dy <= 3; ++dy) {
                    int rb = (y + dy + 3) * TCOLS + xl + 3;
                    const int dxmin = (dy == 0) ? 1 : -3;
#pragma unroll
                    for (int dx = dxmin; dx <= 3; ++dx) {
                        const int j = (dy + 3) * 7 + (dx + 3);
                        CAND(j, rb, dx);
                    }
                }
                kbuf[pidx][0] = s0; kbuf[pidx][1] = s1; kbuf[pidx][2] = s2;
                kbuf[pidx][3] = s3; kbuf[pidx][4] = s4; kbuf[pidx][5] = s5;
                kbuf[pidx][6] = s6;
            }
            if (role == 0) {
                __syncthreads();
                // Batcher half-cleaner: mins of (a_k, b_{6-k}) = 7 smallest of 14
                double m0 = fmin(s0, kbuf[pidx][6]);
                double m1 = fmin(s1, kbuf[pidx][5]);
                double m2 = fmin(s2, kbuf[pidx][4]);
                double m3 = fmin(s3, kbuf[pidx][3]);
                double m4 = fmin(s4, kbuf[pidx][2]);
                double m5 = fmin(s5, kbuf[pidx][1]);
                double m6 = fmin(s6, kbuf[pidx][0]);

                const double cutmax = __longlong_as_double((long long)CUTOFF_KEYMAX);
                int c0, c1, c2, c3, c4, c5, c6;
#define CLSK(MK, CK) do {                                                \
                long long kb = __double_as_longlong(MK);                 \
                int j = (int)(kb & 63);                                  \
                bool sel = (MK) <= cutmax;                               \
                int dy7 = (j * 37) >> 8;                                 \
                int cc = (int)atile[(y + dy7) * TCOLS + xl + (j - dy7 * 7)]; \
                CK = sel ? cc : 0;                                       \
            } while (0)
                CLSK(m0, c0); CLSK(m1, c1); CLSK(m2, c2); CLSK(m3, c3);
                CLSK(m4, c4); CLSK(m5, c5); CLSK(m6, c6);
#undef CLSK

                int n0 = 1, n1 = 1, n2 = 1, n3 = 1, n4 = 1, n5 = 1, n6 = 1;
#define PAIRV(A, B) do { bool e = (c##A == c##B); n##A += e ? 1 : 0; n##B += e ? 1 : 0; } while (0)
                PAIRV(0,1); PAIRV(0,2); PAIRV(0,3); PAIRV(0,4); PAIRV(0,5); PAIRV(0,6);
                PAIRV(1,2); PAIRV(1,3); PAIRV(1,4); PAIRV(1,5); PAIRV(1,6);
                PAIRV(2,3); PAIRV(2,4); PAIRV(2,5); PAIRV(2,6);
                PAIRV(3,4); PAIRV(3,5); PAIRV(3,6);
                PAIRV(4,5); PAIRV(4,6);
                PAIRV(5,6);
#undef PAIRV

                int best = 0;
#define SCORE(K) do {                                                    \
                bool valid = (unsigned)(c##K - 1) < (unsigned)(NCLASSES - 1);\
                int sc = valid ? ((n##K << 5) | (31 - c##K)) : 0;        \
                best = max(best, sc);                                    \
            } while (0)
                SCORE(0); SCORE(1); SCORE(2); SCORE(3); SCORE(4); SCORE(5); SCORE(6);
#undef SCORE
                if (active) outv[i] = (best == 0) ? 1 : (31 - (best & 31));
                __syncthreads();             // matches role-1's barriers below
            } else {
                __syncthreads();
                __syncthreads();
            }
        } else {
            __syncthreads();
            __syncthreads();
        }
    }
}

extern "C" void kernel_launch(void* const* d_in, const int* in_sizes, int n_in,
                              void* d_out, int out_size, void* d_ws, size_t ws_size,
                              hipStream_t stream) {
    const float* proj_range   = (const float*)d_in[0];
    const float* unproj_range = (const float*)d_in[1];
    const int*   proj_argmax  = (const int*)d_in[2];
    const int*   px           = (const int*)d_in[3];
    const int*   py           = (const int*)d_in[4];
    int* out = (int*)d_out;

    // Emulate numpy float32 pipeline for the inverse-gaussian table.
    InvG invg;
    float g[S2];
    for (int yy = 0; yy < SEARCH; ++yy) {
        for (int xx = 0; xx < SEARCH; ++xx) {
            float fdx = (float)xx - 3.0f;
            float fdy = (float)yy - 3.0f;
            float s   = fdx * fdx + fdy * fdy;
            float arg = -s / 2.0f;
            float e   = (float)exp((double)arg);
            float gg  = e / 6.2831855f;
            g[yy * SEARCH + xx] = gg;
        }
    }
    float r[8];
    for (int tt = 0; tt < 8; ++tt) r[tt] = g[tt];
    int ii;
    for (ii = 8; ii + 8 <= 48; ii += 8)
        for (int tt = 0; tt < 8; ++tt) r[tt] += g[ii + tt];
    float ssum = ((r[0] + r[1]) + (r[2] + r[3])) + ((r[4] + r[5]) + (r[6] + r[7]));
    for (; ii < S2; ++ii) ssum += g[ii];
    for (int tt = 0; tt < S2; ++tt) invg.v[tt] = 1.0f - (g[tt] / ssum);

    knn_kernel<<<NTILES * SPT, KBLOCK, 0, stream>>>(
        proj_range, unproj_range, proj_argmax, px, py, out, invg);
}